// Round 9
// baseline (750.291 us; speedup 1.0000x reference)
//
#include <hip/hip_runtime.h>

typedef short short8 __attribute__((ext_vector_type(8)));
typedef float f32x4 __attribute__((ext_vector_type(4)));

#define MFMA16(a, b, c) __builtin_amdgcn_mfma_f32_16x16x32_bf16(a, b, c, 0, 0, 0)

static __device__ __forceinline__ unsigned short f2bf(float f) {
  union { float f; unsigned u; } v; v.f = f;
  return (unsigned short)((v.u + 0x7FFFu + ((v.u >> 16) & 1u)) >> 16);
}
static __device__ __forceinline__ unsigned pk2(float a, float b) {
  return (unsigned)f2bf(a) | ((unsigned)f2bf(b) << 16);
}
static __device__ __forceinline__ float bf2f(unsigned short u) {
  union { unsigned u; float f; } v; v.u = ((unsigned)u) << 16; return v.f;
}
static __device__ __forceinline__ void async16(void* lds, const void* g) {
  __builtin_amdgcn_global_load_lds(
      (const __attribute__((address_space(1))) unsigned*)g,
      (__attribute__((address_space(3))) unsigned*)lds, 16, 0, 0);
}
static __device__ __forceinline__ float wsum64(float v) {
#pragma unroll
  for (int m = 1; m < 64; m <<= 1) v += __shfl_xor(v, m);
  return v;
}

#define LOAD4(B, P)                                   \
  {                                                   \
    const unsigned short* _p = (P);                   \
    B[0] = *(const short8*)(_p);                      \
    B[1] = *(const short8*)(_p + 512);                \
    B[2] = *(const short8*)(_p + 1024);               \
    B[3] = *(const short8*)(_p + 1536);               \
  }

// ---------------- K1: prep — pack weights + parallel wk + zero ----
// w1f per (e,fq) 64KB: [set 8 (=kc*2+ks)][wv_f 2][fr 4][lane 64][8 bf16]
// w2f per (e,fq) 64KB: [kc2 4][wv_h 4][hr 4][lane 64][8 bf16]
// wpt: 8 chunks [fl 128][kk 64] swizzled (k_proj format)
// wk: 16 blocks (2 Wq x 8 k-slabs x 32 rows), keys^T staged in LDS
__global__ void k_prep(const float* __restrict__ w1, const float* __restrict__ w2,
                       const float* __restrict__ Wp, const float* __restrict__ Wq1,
                       const float* __restrict__ Wq2, const float* __restrict__ keys,
                       unsigned short* __restrict__ w1f, unsigned short* __restrict__ w2f,
                       unsigned short* __restrict__ wpt, float* __restrict__ wk1,
                       float* __restrict__ wk2, float* __restrict__ dout) {
  __shared__ __align__(16) short T[64 * 266];
  const int b = blockIdx.x, tid = threadIdx.x;
  if (b < 512) {
    // w1 chunk: b = e*16 + fq*4 + kc; 64 k-rows x 128 f-cols
    int e = b >> 4, fq = (b >> 2) & 3, kc = b & 3;
    const float* src = w1 + (e * 256 + kc * 64) * 512 + fq * 128;
    for (int c = tid; c < 1024; c += 256) {
      int hr = c >> 4, c8 = c & 15;
      const float* s = src + hr * 512 + c8 * 8;
      f32x4 v0 = *(const f32x4*)s;
      f32x4 v1 = *(const f32x4*)(s + 4);
      unsigned* tp = (unsigned*)(T + hr * 138 + c8 * 8);
      tp[0] = pk2(v0.x, v0.y); tp[1] = pk2(v0.z, v0.w);
      tp[2] = pk2(v1.x, v1.y); tp[3] = pk2(v1.z, v1.w);
    }
    __syncthreads();
#pragma unroll
    for (int j = 0; j < 4; ++j) {
      int o = tid + j * 256;
      int fl = o >> 3, k8 = o & 7;
      unsigned qq[4];
#pragma unroll
      for (int p = 0; p < 4; ++p) {
        unsigned a0 = (unsigned short)T[(k8 * 8 + p * 2) * 138 + fl];
        unsigned a1 = (unsigned short)T[(k8 * 8 + p * 2 + 1) * 138 + fl];
        qq[p] = a0 | (a1 << 16);
      }
      uint4 q; q.x = qq[0]; q.y = qq[1]; q.z = qq[2]; q.w = qq[3];
      int set = kc * 2 + (k8 >> 2);
      int lane = (k8 & 3) * 16 + (fl & 15);
      int wvf = fl >> 6, fr = (fl >> 4) & 3;
      *(uint4*)(w1f + (size_t)(e * 4 + fq) * 32768 + set * 4096 + wvf * 2048 + fr * 512 +
                lane * 8) = q;
    }
  } else if (b < 768) {
    // w2 chunk: b2 = e*8 + fq*2 + kcc; 64 f-rows x 256 hd
    int b2 = b - 512;
    int e = b2 >> 3, fq = (b2 >> 1) & 3, kcc = b2 & 1;
    const float* src = w2 + (e * 512 + fq * 128 + kcc * 64) * 256;
    for (int c = tid; c < 2048; c += 256) {
      int fr = c >> 5, c8 = c & 31;
      const float* s = src + fr * 256 + c8 * 8;
      f32x4 v0 = *(const f32x4*)s;
      f32x4 v1 = *(const f32x4*)(s + 4);
      unsigned* tp = (unsigned*)(T + fr * 266 + c8 * 8);
      tp[0] = pk2(v0.x, v0.y); tp[1] = pk2(v0.z, v0.w);
      tp[2] = pk2(v1.x, v1.y); tp[3] = pk2(v1.z, v1.w);
    }
    __syncthreads();
#pragma unroll
    for (int j = 0; j < 8; ++j) {
      int o = tid + j * 256;
      int hd = o >> 3, k8 = o & 7;
      unsigned qq[4];
#pragma unroll
      for (int p = 0; p < 4; ++p) {
        unsigned a0 = (unsigned short)T[(k8 * 8 + p * 2) * 266 + hd];
        unsigned a1 = (unsigned short)T[(k8 * 8 + p * 2 + 1) * 266 + hd];
        qq[p] = a0 | (a1 << 16);
      }
      uint4 q; q.x = qq[0]; q.y = qq[1]; q.z = qq[2]; q.w = qq[3];
      int kc2 = kcc * 2 + (k8 >> 2);
      int lane = (k8 & 3) * 16 + (hd & 15);
      *(uint4*)(w2f + (size_t)(e * 4 + fq) * 32768 + kc2 * 8192 + (hd >> 4) * 512 +
                lane * 8) = q;
    }
  } else if (b < 776) {
    int b3 = b - 768;
    int fq = b3 >> 2, kc = b3 & 3;
    const float* src = Wp + (kc * 64) * 256 + fq * 128;
    for (int c = tid; c < 1024; c += 256) {
      int hr = c >> 4, c8 = c & 15;
      const float* s = src + hr * 256 + c8 * 8;
      f32x4 v0 = *(const f32x4*)s;
      f32x4 v1 = *(const f32x4*)(s + 4);
      unsigned* tp = (unsigned*)(T + hr * 138 + c8 * 8);
      tp[0] = pk2(v0.x, v0.y); tp[1] = pk2(v0.z, v0.w);
      tp[2] = pk2(v1.x, v1.y); tp[3] = pk2(v1.z, v1.w);
    }
    __syncthreads();
#pragma unroll
    for (int j = 0; j < 4; ++j) {
      int o = tid + j * 256;
      int fl = o >> 3, k8 = o & 7;
      unsigned qq[4];
#pragma unroll
      for (int p = 0; p < 4; ++p) {
        unsigned a0 = (unsigned short)T[(k8 * 8 + p * 2) * 138 + fl];
        unsigned a1 = (unsigned short)T[(k8 * 8 + p * 2 + 1) * 138 + fl];
        qq[p] = a0 | (a1 << 16);
      }
      uint4 q; q.x = qq[0]; q.y = qq[1]; q.z = qq[2]; q.w = qq[3];
      int off = (fl * 64 + k8 * 8) ^ ((fl & 7) << 3);
      *(uint4*)(wpt + b3 * 8192 + off) = q;
    }
  } else if (b < 792) {
    // wk: Wk[k][e] = sum_j Wq[k][j]*keys[e][j]; 8 blocks of 32 k-rows per Wq
    int b4 = b - 776;
    const float* Wq = (b4 >= 8) ? Wq2 : Wq1;
    float* Wk = (b4 >= 8) ? wk2 : wk1;
    const int kb = (b4 & 7) * 32;
    float* KT = (float*)T;  // [j 256][e 32], rotated: col = (e + j) & 31
    for (int i = tid; i < 8192; i += 256) {
      int e = i >> 8, j = i & 255;
      KT[j * 32 + ((e + j) & 31)] = keys[e * 256 + j];
    }
    __syncthreads();
    const int e = tid & 31, kk = (tid >> 5) * 2;  // 2 k-rows per thread
    f32x4 acc0 = (f32x4)(0.0f), acc1 = (f32x4)(0.0f);
    const float* wq0 = Wq + (size_t)(kb + kk) * 256;
#pragma unroll 4
    for (int j = 0; j < 256; j += 4) {
      f32x4 kt;
      kt.x = KT[j * 32 + ((e + j) & 31)];
      kt.y = KT[(j + 1) * 32 + ((e + j + 1) & 31)];
      kt.z = KT[(j + 2) * 32 + ((e + j + 2) & 31)];
      kt.w = KT[(j + 3) * 32 + ((e + j + 3) & 31)];
      acc0 += *(const f32x4*)(wq0 + j) * kt;
      acc1 += *(const f32x4*)(wq0 + 256 + j) * kt;
    }
    Wk[(kb + kk) * 32 + e] = acc0.x + acc0.y + acc0.z + acc0.w;
    Wk[(kb + kk + 1) * 32 + e] = acc1.x + acc1.y + acc1.z + acc1.w;
  } else {
    for (int i = tid; i < 2048; i += 256) dout[i] = 0.0f;
    if (tid == 0) dout[2048 + 4194304] = 0.0f;
  }
}

// ---------------- K2: input projection (MFMA, unchanged) ----------------
#define P_LDS_W 67584
#define P_LDS_BP 100352
#define P_LDS_TOT 101376

__launch_bounds__(512, 2)
__global__ void k_proj(const float* __restrict__ xin, const unsigned short* __restrict__ wpt,
                       const float* __restrict__ bp, float* __restrict__ tokf,
                       unsigned short* __restrict__ tokb) {
  extern __shared__ char smem[];
  const int tid = threadIdx.x;
  const int tb = blockIdx.x * 128;
  const int w = tid >> 6, l = tid & 63, l15 = l & 15, l4 = l >> 4;

  for (int s = tid; s < 4096; s += 512) {
    int row = s >> 5, c8 = s & 31;
    const float* src = xin + (tb + row) * 256 + c8 * 8;
    f32x4 v0 = *(const f32x4*)src;
    f32x4 v1 = *(const f32x4*)(src + 4);
    uint4 pv;
    pv.x = pk2(v0.x, v0.y); pv.y = pk2(v0.z, v0.w);
    pv.z = pk2(v1.x, v1.y); pv.w = pk2(v1.z, v1.w);
    *(uint4*)(smem + row * 528 + c8 * 16) = pv;
  }
  if (tid < 256) ((float*)(smem + P_LDS_BP))[tid] = bp[tid];
  __syncthreads();

  const int wv_f = w >> 2, wv_t = w & 3;
  for (int fq = 0; fq < 2; ++fq) {
    f32x4 acc[8];
#pragma unroll
    for (int i = 0; i < 8; ++i) acc[i] = (f32x4)(0.0f);
    const char* cbase = (const char*)(wpt + (fq * 4) * 8192);
    {
      char* dst = smem + P_LDS_W;
      async16(dst + w * 2048, cbase + w * 2048 + l * 16);
      async16(dst + w * 2048 + 1024, cbase + w * 2048 + 1024 + l * 16);
    }
    __syncthreads();
    for (int kc = 0; kc < 4; ++kc) {
      int cur = kc & 1;
      if (kc < 3) {
        char* dst = smem + P_LDS_W + (cur ^ 1) * 16384;
        const char* src = cbase + (kc + 1) * 16384;
        async16(dst + w * 2048, src + w * 2048 + l * 16);
        async16(dst + w * 2048 + 1024, src + w * 2048 + 1024 + l * 16);
      }
      const char* Wc = smem + P_LDS_W + cur * 16384;
#pragma unroll
      for (int ks = 0; ks < 2; ++ks) {
        short8 af[4], bfr[2];
#pragma unroll
        for (int fr = 0; fr < 4; ++fr) {
          int frow = wv_f * 64 + fr * 16 + l15;
          int off = (frow * 128 + ks * 64 + l4 * 16) ^ ((frow & 7) << 4);
          af[fr] = *(const short8*)(Wc + off);
        }
#pragma unroll
        for (int tf = 0; tf < 2; ++tf) {
          int tok = wv_t * 32 + tf * 16 + l15;
          bfr[tf] = *(const short8*)(smem + tok * 528 + kc * 128 + ks * 64 + l4 * 16);
        }
#pragma unroll
        for (int fr = 0; fr < 4; ++fr)
#pragma unroll
          for (int tf = 0; tf < 2; ++tf)
            acc[fr * 2 + tf] = MFMA16(af[fr], bfr[tf], acc[fr * 2 + tf]);
      }
      __syncthreads();
    }
    const float* BP = (const float*)(smem + P_LDS_BP);
#pragma unroll
    for (int fr = 0; fr < 4; ++fr) {
      int hd0 = fq * 128 + wv_f * 64 + fr * 16 + l4 * 4;
      f32x4 bv = *(const f32x4*)(BP + hd0);
#pragma unroll
      for (int tf = 0; tf < 2; ++tf) {
        int tok = tb + wv_t * 32 + tf * 16 + l15;
        f32x4 o = acc[fr * 2 + tf] + bv;
        *(f32x4*)(tokf + tok * 256 + hd0) = o;
        uint2 hv; hv.x = pk2(o.x, o.y); hv.y = pk2(o.z, o.w);
        *(uint2*)(tokb + tok * 256 + hd0) = hv;
      }
    }
  }
}

// ---------------- K3: router 1 (fp32, unchanged) ----------------
__global__ void k_router1(const float* __restrict__ tokf, const float* __restrict__ wk1,
                          float* __restrict__ probs1, int* __restrict__ top1) {
  __shared__ float WK[8192];
  const int tid = threadIdx.x;
  for (int i = tid; i < 8192; i += 256) WK[i] = wk1[i];
  __syncthreads();
  const int w = tid >> 6, l = tid & 63;
  const int e = l & 31, half = l >> 5;
  for (int tt = 0; tt < 16; ++tt) {
    int t = blockIdx.x * 64 + w * 16 + tt;
    const float* row = tokf + t * 256 + half * 128;
    const float* wkh = WK + half * 128 * 32 + e;
    float s = 0.f;
    for (int kk = 0; kk < 128; ++kk) s += row[kk] * wkh[kk * 32];
    s += __shfl_xor(s, 32);
    s *= 0.0625f;
    float m = s;
#pragma unroll
    for (int off = 16; off > 0; off >>= 1) m = fmaxf(m, __shfl_xor(m, off, 32));
    float ex = __expf(s - m);
    float sum = ex;
#pragma unroll
    for (int off = 16; off > 0; off >>= 1) sum += __shfl_xor(sum, off, 32);
    if (l < 32) probs1[t * 32 + e] = ex / sum;
    float bs = s; int bi = e;
#pragma unroll
    for (int off = 16; off > 0; off >>= 1) {
      float os = __shfl_xor(bs, off, 32);
      int oi = __shfl_xor(bi, off, 32);
      if (os > bs || (os == bs && oi < bi)) { bs = os; bi = oi; }
    }
    if (l == 0) top1[t] = bi;
  }
}

// ---------------- K4: fused expert bank (flatmm + 3-deep 4-ring) ----
#define B_PR 65536
#define B_B1 73728
#define B_TOT 106496

__launch_bounds__(512, 2)
__global__ void k_bank(const unsigned short* __restrict__ xg, const float* __restrict__ probsg,
                       const float* __restrict__ b1g, const unsigned short* __restrict__ w1f,
                       const unsigned short* __restrict__ w2f, float* __restrict__ partg) {
  extern __shared__ char smem[];
  const int tid = threadIdx.x;
  // XCD-coherent mapping: each XCD's blocks share one expert-group weight slab.
  const int xcd = blockIdx.x & 7;
  const int grp = xcd >> 2;
  const int tile = (xcd & 3) * 32 + (blockIdx.x >> 3);
  const int tb = tile * 128;
  const int w = tid >> 6, l = tid & 63, l15 = l & 15, l4 = l >> 4;
  const int wv_f = w >> 2, wv_t = w & 3;   // G1: 2 f-halves x 4 tok-groups
  const int wv_h = w >> 1, wv_t2 = w & 1;  // G2: 4 hd-groups x 2 tok-halves
  float* PRL = (float*)(smem + B_PR);
  float* B1L = (float*)(smem + B_B1);

  // stage probs (16e x 128tok) + b1 slab (16e x 512)
  for (int s = tid; s < 2048; s += 512)
    PRL[s] = probsg[(size_t)(tb + (s & 127)) * 32 + grp * 16 + (s >> 7)];
  for (int s = tid; s < 8192; s += 512) B1L[s] = b1g[grp * 8192 + s];

  // X fragments -> registers
  short8 xr[16];
#pragma unroll
  for (int tf = 0; tf < 2; ++tf)
#pragma unroll
    for (int kc = 0; kc < 4; ++kc)
#pragma unroll
      for (int ks = 0; ks < 2; ++ks) {
        int tok = tb + wv_t * 32 + tf * 16 + l15;
        xr[tf * 8 + kc * 2 + ks] =
            *(const short8*)(xg + (size_t)tok * 256 + kc * 64 + ks * 32 + l4 * 8);
      }
  __syncthreads();

  const unsigned short* w1e = w1f + (size_t)grp * 64 * 32768;
  const unsigned short* w2e = w2f + (size_t)grp * 64 * 32768;
  const int o1 = wv_f * 2048 + l * 8;
  const int o2 = wv_h * 2048 + l * 8;

  f32x4 acc2[16];
#pragma unroll
  for (int i = 0; i < 16; ++i) acc2[i] = (f32x4)(0.0f);

  // 4-buffer ring, prefetch distance 3. 12 sets/el; slot = set & 3 (12%4==0).
  short8 wb[4][4];
  LOAD4(wb[0], w1e + 0 * 4096 + o1);  // el0 set0
  LOAD4(wb[1], w1e + 1 * 4096 + o1);  // el0 set1
  LOAD4(wb[2], w1e + 2 * 4096 + o1);  // el0 set2
  int hcur = 0;

  for (int el = 0; el < 64; ++el) {
    const unsigned short* w1c = w1e + (size_t)el * 32768;
    const unsigned short* w2c = w2e + (size_t)el * 32768;
    const int e = el >> 2, fq = el & 3;

    // ---- G1: sets 0..7; issue set k+3 (crosses into this el's G2 sets)
    f32x4 acc1[8];
#pragma unroll
    for (int i = 0; i < 8; ++i) acc1[i] = (f32x4)(0.0f);
#pragma unroll
    for (int k = 0; k < 8; ++k) {
      const int t = k + 3;
      if (t < 8) { LOAD4(wb[t & 3], w1c + t * 4096 + o1); }
      else       { LOAD4(wb[t & 3], w2c + (t - 8) * 8192 + o2); }
      __builtin_amdgcn_s_setprio(1);
#pragma unroll
      for (int fr = 0; fr < 4; ++fr)
#pragma unroll
        for (int tf = 0; tf < 2; ++tf)
          acc1[fr * 2 + tf] = MFMA16(wb[k & 3][fr], xr[tf * 8 + k], acc1[fr * 2 + tf]);
      __builtin_amdgcn_s_setprio(0);
    }

    // ---- epilogue: h = relu(acc1 + b1)*p -> H[hcur]
    {
      const float* bb = B1L + e * 512 + fq * 128;
      const float* pp = PRL + e * 128;
      float p0 = pp[wv_t * 32 + l15];
      float p1 = pp[wv_t * 32 + 16 + l15];
      char* Hw = smem + hcur * 32768;
#pragma unroll
      for (int fr = 0; fr < 4; ++fr) {
        int f0 = wv_f * 64 + fr * 16 + l4 * 4;
        f32x4 bvv = *(const f32x4*)(bb + f0);
#pragma unroll
        for (int tf = 0; tf < 2; ++tf) {
          int tok = wv_t * 32 + tf * 16 + l15;
          float p = tf ? p1 : p0;
          f32x4 a = acc1[fr * 2 + tf];
          float h0 = fmaxf(a.x + bvv.x, 0.f) * p;
          float h1 = fmaxf(a.y + bvv.y, 0.f) * p;
          float h2 = fmaxf(a.z + bvv.z, 0.f) * p;
          float h3 = fmaxf(a.w + bvv.w, 0.f) * p;
          uint2 hv; hv.x = pk2(h0, h1); hv.y = pk2(h2, h3);
          *(uint2*)(Hw + ((tok * 256 + f0 * 2) ^ ((tok & 7) << 4))) = hv;
        }
      }
    }
    __syncthreads();  // single barrier per el (H dbuf)

    // ---- G2: sets 8..11; issue set k+3 (w2 set3, then next-el w1 sets 0..2)
    {
      const char* Hr = smem + hcur * 32768;
#pragma unroll
      for (int k = 8; k < 12; ++k) {
        const int t = k + 3;
        if (t < 12)       { LOAD4(wb[t & 3], w2c + (t - 8) * 8192 + o2); }
        else if (el < 63) { LOAD4(wb[t & 3], w1c + 32768 + (t - 12) * 4096 + o1); }
        short8 b2f[4];
#pragma unroll
        for (int tf = 0; tf < 4; ++tf) {
          int tok = wv_t2 * 64 + tf * 16 + l15;
          b2f[tf] = *(const short8*)(
              Hr + ((tok * 256 + (k - 8) * 64 + l4 * 16) ^ ((tok & 7) << 4)));
        }
        __builtin_amdgcn_s_setprio(1);
#pragma unroll
        for (int hr = 0; hr < 4; ++hr)
#pragma unroll
          for (int tf = 0; tf < 4; ++tf)
            acc2[hr * 4 + tf] = MFMA16(wb[k & 3][hr], b2f[tf], acc2[hr * 4 + tf]);
        __builtin_amdgcn_s_setprio(0);
      }
    }
    hcur ^= 1;
  }

  float* pout = partg + (size_t)grp * 4194304;
#pragma unroll
  for (int hr = 0; hr < 4; ++hr) {
    int hd0 = wv_h * 64 + hr * 16 + l4 * 4;
#pragma unroll
    for (int tf = 0; tf < 4; ++tf) {
      int tok = tb + wv_t2 * 64 + tf * 16 + l15;
      *(f32x4*)(pout + (size_t)tok * 256 + hd0) = acc2[hr * 4 + tf];
    }
  }
}

// ---------------- K5: hop1 reduce + halt + router2 ----------------
#define M_PRB 65536
#define M_AUX 73728
#define M_TBL 106496
#define M_PSUM 110592
#define M_TOT 110656

__launch_bounds__(512)
__global__ void k_mid(const float* __restrict__ partg, const float* __restrict__ probs1,
                      const float* __restrict__ b2g, const float* __restrict__ hlg,
                      const float* __restrict__ hlb, const float* __restrict__ hwg,
                      const float* __restrict__ hbg, const float* __restrict__ wk2,
                      const float* __restrict__ tbias, const int* __restrict__ top1,
                      unsigned short* __restrict__ hop1b, float* __restrict__ haltg,
                      float* __restrict__ probs2, float* __restrict__ dout) {
  extern __shared__ char smem[];
  const int tid = threadIdx.x;
  const int tb = blockIdx.x * 64;
  float* ROWS = (float*)smem;
  float* PRB = (float*)(smem + M_PRB);
  float* AUX = (float*)(smem + M_AUX);

  for (int i = tid; i < 2048; i += 512) PRB[i] = probs1[tb * 32 + i];
  for (int i = tid; i < 8192; i += 512) AUX[i] = b2g[i];
  __syncthreads();

  for (int i = tid; i < 4096; i += 512) {
    int t = i >> 6, h4 = i & 63;
    size_t gi = (size_t)(tb + t) * 256 + h4 * 4;
    f32x4 v = *(const f32x4*)(partg + gi) + *(const f32x4*)(partg + 4194304 + gi);
    const float* pr = PRB + t * 32;
    for (int e = 0; e < 32; ++e) v += pr[e] * *(const f32x4*)(AUX + e * 256 + h4 * 4);
    *(f32x4*)(ROWS + t * 256 + h4 * 4) = v;
    uint2 hv; hv.x = pk2(v.x, v.y); hv.y = pk2(v.z, v.w);
    *(uint2*)(hop1b + gi) = hv;
  }
  __syncthreads();
  for (int i = tid; i < 8192; i += 512) AUX[i] = wk2[i];
  float* TBL = (float*)(smem + M_TBL);
  for (int i = tid; i < 1024; i += 512) TBL[i] = tbias[i];
  __syncthreads();

  const int w = tid >> 6, l = tid & 63;
  const int e = l & 31, half = l >> 5;
  float pond = 0.f;
  for (int tt = 0; tt < 8; ++tt) {
    int t = w * 8 + tt, tg = tb + t;
    const float* row = ROWS + t * 256;
    f32x4 x4 = *(const f32x4*)(row + l * 4);
    float mu = wsum64(x4.x + x4.y + x4.z + x4.w) * (1.f / 256.f);
    f32x4 d = x4 - mu;
    float var = wsum64(d.x * d.x + d.y * d.y + d.z * d.z + d.w * d.w) * (1.f / 256.f);
    float rstd = rsqrtf(var + 1e-5f);
    f32x4 g4 = *(const f32x4*)(hlg + l * 4);
    f32x4 b4 = *(const f32x4*)(hlb + l * 4);
    f32x4 w4 = *(const f32x4*)(hwg + l * 4);
    f32x4 y = d * rstd * g4 + b4;
    float z = wsum64(y.x * w4.x + y.y * w4.y + y.z * w4.z + y.w * w4.w);
    float hp = 1.f / (1.f + __expf(-(z + hbg[0])));
    if (l == 0) { haltg[tg] = hp; pond += 1.f - hp; }
    const float* rh = row + half * 128;
    const float* wkh = AUX + half * 128 * 32 + e;
    float sc = 0.f;
    for (int kk = 0; kk < 128; ++kk) sc += rh[kk] * wkh[kk * 32];
    sc += __shfl_xor(sc, 32);
    sc = sc * 0.0625f + TBL[top1[tg] * 32 + e];
    float m = sc;
#pragma unroll
    for (int off = 16; off > 0; off >>= 1) m = fmaxf(m, __shfl_xor(m, off, 32));
    float ex = __expf(sc - m);
    float sum = ex;
#pragma unroll
    for (int off = 16; off > 0; off >>= 1) sum += __shfl_xor(sum, off, 32);
    if (l < 32) probs2[tg * 32 + e] = ex / sum;
  }
  float* PS = (float*)(smem + M_PSUM);
  if (l == 0) PS[w] = pond;
  __syncthreads();
  if (tid == 0) {
    float tot = 0.f;
    for (int i = 0; i < 8; ++i) tot += PS[i];
    atomicAdd(dout + 2048 + 4194304, tot * (0.01f / 16384.f));
  }
}

// ---------------- K7: final mix + LN + pooled ----------------
#define F_PRB 65536
#define F_B2 73728
#define F_PSUM 106496
#define F_TOT 114688

__launch_bounds__(512)
__global__ void k_final(const float* __restrict__ partg, const float* __restrict__ probs2,
                        const float* __restrict__ b2g, const float* __restrict__ tokf,
                        const unsigned short* __restrict__ hop1b, const float* __restrict__ haltg,
                        const float* __restrict__ ng, const float* __restrict__ nbv,
                        float* __restrict__ dout) {
  extern __shared__ char smem[];
  const int tid = threadIdx.x;
  const int tb = blockIdx.x * 64;
  const int batch = blockIdx.x >> 5;
  float* ROWS = (float*)smem;
  float* PRB = (float*)(smem + F_PRB);
  float* B2L = (float*)(smem + F_B2);

  for (int i = tid; i < 2048; i += 512) PRB[i] = probs2[tb * 32 + i];
  for (int i = tid; i < 8192; i += 512) B2L[i] = b2g[i];
  __syncthreads();

  for (int i = tid; i < 4096; i += 512) {
    int t = i >> 6, h4 = i & 63;
    size_t gi = (size_t)(tb + t) * 256 + h4 * 4;
    f32x4 h2 = *(const f32x4*)(partg + gi) + *(const f32x4*)(partg + 4194304 + gi);
    const float* pr = PRB + t * 32;
    for (int e = 0; e < 32; ++e) h2 += pr[e] * *(const f32x4*)(B2L + e * 256 + h4 * 4);
    float hp = haltg[tb + t];
    uint2 h1v = *(const uint2*)(hop1b + gi);
    f32x4 h1;
    h1.x = bf2f(h1v.x & 0xffff); h1.y = bf2f(h1v.x >> 16);
    h1.z = bf2f(h1v.y & 0xffff); h1.w = bf2f(h1v.y >> 16);
    f32x4 tk = *(const f32x4*)(tokf + gi);
    f32x4 pre = tk + hp * h1 + (1.f - hp) * h2;
    *(f32x4*)(ROWS + t * 256 + h4 * 4) = pre;
  }
  __syncthreads();
  const int w = tid >> 6, l = tid & 63;
  f32x4 pacc = (f32x4)(0.0f);
  f32x4 g4 = *(const f32x4*)(ng + l * 4);
  f32x4 b4 = *(const f32x4*)(nbv + l * 4);
  for (int tt = 0; tt < 8; ++tt) {
    int t = w * 8 + tt, tg = tb + t;
    f32x4 x4 = *(const f32x4*)(ROWS + t * 256 + l * 4);
    float mu = wsum64(x4.x + x4.y + x4.z + x4.w) * (1.f / 256.f);
    f32x4 d = x4 - mu;
    float var = wsum64(d.x * d.x + d.y * d.y + d.z * d.z + d.w * d.w) * (1.f / 256.f);
    float rstd = rsqrtf(var + 1e-5f);
    f32x4 y = d * rstd * g4 + b4;
    *(f32x4*)(dout + 2048 + (size_t)tg * 256 + l * 4) = y;
    pacc += y;
  }
  float* PS = (float*)(smem + F_PSUM);
  *(f32x4*)(PS + w * 256 + l * 4) = pacc;
  __syncthreads();
  if (tid < 256) {
    float s = 0.f;
    for (int ww = 0; ww < 8; ++ww) s += PS[ww * 256 + tid];
    atomicAdd(dout + batch * 256 + tid, s * (1.f / 2048.f));
  }
}

extern "C" void kernel_launch(void* const* d_in, const int* in_sizes, int n_in,
                              void* d_out, int out_size, void* d_ws, size_t ws_size,
                              hipStream_t stream) {
  (void)in_sizes; (void)n_in; (void)out_size; (void)ws_size;
  const float* tokens_in = (const float*)d_in[0];
  const float* Wp = (const float*)d_in[1];
  const float* bp = (const float*)d_in[2];
  const float* Wq1 = (const float*)d_in[3];
  const float* Wq2 = (const float*)d_in[4];
  const float* keys = (const float*)d_in[5];
  const float* tbias = (const float*)d_in[6];
  const float* hlg = (const float*)d_in[7];
  const float* hlb = (const float*)d_in[8];
  const float* hw = (const float*)d_in[9];
  const float* hb = (const float*)d_in[10];
  const float* w1 = (const float*)d_in[11];
  const float* b1 = (const float*)d_in[12];
  const float* w2 = (const float*)d_in[13];
  const float* b2 = (const float*)d_in[14];
  const float* ng = (const float*)d_in[15];
  const float* nb = (const float*)d_in[16];
  float* out = (float*)d_out;
  char* ws = (char*)d_ws;

  unsigned short* w1f = (unsigned short*)(ws + 0);
  unsigned short* w2f = (unsigned short*)(ws + 8388608);
  unsigned short* wpt = (unsigned short*)(ws + 16777216);
  float* tokf = (float*)(ws + 16908288);
  unsigned short* tokb = (unsigned short*)(ws + 33685504);
  float* probs1 = (float*)(ws + 42074112);
  int* top1 = (int*)(ws + 44171264);
  unsigned short* hop1b = (unsigned short*)(ws + 44236800);
  float* haltg = (float*)(ws + 52625408);
  float* probs2 = (float*)(ws + 52690944);
  float* wk1 = (float*)(ws + 54788096);
  float* wk2 = (float*)(ws + 54820864);
  float* part = (float*)(ws + 54853632);  // 2 x 16384 x 256 f32

  k_prep<<<dim3(793), dim3(256), 0, stream>>>(w1, w2, Wp, Wq1, Wq2, keys,
                                              w1f, w2f, wpt, wk1, wk2, out);
  k_proj<<<dim3(128), dim3(512), P_LDS_TOT, stream>>>(tokens_in, wpt, bp, tokf, tokb);
  k_router1<<<dim3(256), dim3(256), 0, stream>>>(tokf, wk1, probs1, top1);
  k_bank<<<dim3(256), dim3(512), B_TOT, stream>>>(tokb, probs1, b1, w1f, w2f, part);
  k_mid<<<dim3(256), dim3(512), M_TOT, stream>>>(part, probs1, b2, hlg, hlb, hw, hb, wk2,
                                                 tbias, top1, hop1b, haltg, probs2, out);
  k_bank<<<dim3(256), dim3(512), B_TOT, stream>>>(hop1b, probs2, b1, w1f, w2f, part);
  k_final<<<dim3(256), dim3(512), F_TOT, stream>>>(part, probs2, b2, tokf, hop1b, haltg, ng, nb, out);
}

// Round 10
// 646.985 us; speedup vs baseline: 1.1597x; 1.1597x over previous
//
#include <hip/hip_runtime.h>

typedef short short8 __attribute__((ext_vector_type(8)));
typedef float f32x4 __attribute__((ext_vector_type(4)));

#define MFMA16(a, b, c) __builtin_amdgcn_mfma_f32_16x16x32_bf16(a, b, c, 0, 0, 0)

// HW packed f32->bf16 (RNE), 1 inst per 2 values (gfx950; no builtin -> asm)
static __device__ __forceinline__ unsigned pk2(float a, float b) {
  unsigned r;
  asm("v_cvt_pk_bf16_f32 %0, %1, %2" : "=v"(r) : "v"(a), "v"(b));
  return r;
}
static __device__ __forceinline__ float bf2f(unsigned short u) {
  union { unsigned u; float f; } v; v.u = ((unsigned)u) << 16; return v.f;
}
static __device__ __forceinline__ void async16(void* lds, const void* g) {
  __builtin_amdgcn_global_load_lds(
      (const __attribute__((address_space(1))) unsigned*)g,
      (__attribute__((address_space(3))) unsigned*)lds, 16, 0, 0);
}
static __device__ __forceinline__ float wsum64(float v) {
#pragma unroll
  for (int m = 1; m < 64; m <<= 1) v += __shfl_xor(v, m);
  return v;
}

#define LOAD4(B, P)                                   \
  {                                                   \
    const unsigned short* _p = (P);                   \
    B[0] = *(const short8*)(_p);                      \
    B[1] = *(const short8*)(_p + 512);                \
    B[2] = *(const short8*)(_p + 1024);               \
    B[3] = *(const short8*)(_p + 1536);               \
  }

// ---------------- K1: prep — pack weights + parallel wk + zero ----
// w1f per (e,fq) 64KB: [set 8 (=kc*2+ks)][wv_f 2][fr 4][lane 64][8 bf16]
// w2f per (e,fq) 64KB: [kc2 4][wv_h 4][hr 4][lane 64][8 bf16]
// wpt: 8 chunks [fl 128][kk 64] swizzled (k_proj format)
// wk: 16 blocks (2 Wq x 8 k-slabs x 32 rows), keys^T staged in LDS
__global__ void k_prep(const float* __restrict__ w1, const float* __restrict__ w2,
                       const float* __restrict__ Wp, const float* __restrict__ Wq1,
                       const float* __restrict__ Wq2, const float* __restrict__ keys,
                       unsigned short* __restrict__ w1f, unsigned short* __restrict__ w2f,
                       unsigned short* __restrict__ wpt, float* __restrict__ wk1,
                       float* __restrict__ wk2, float* __restrict__ dout) {
  __shared__ __align__(16) short T[64 * 266];
  const int b = blockIdx.x, tid = threadIdx.x;
  if (b < 512) {
    // w1 chunk: b = e*16 + fq*4 + kc; 64 k-rows x 128 f-cols
    int e = b >> 4, fq = (b >> 2) & 3, kc = b & 3;
    const float* src = w1 + (e * 256 + kc * 64) * 512 + fq * 128;
    for (int c = tid; c < 1024; c += 256) {
      int hr = c >> 4, c8 = c & 15;
      const float* s = src + hr * 512 + c8 * 8;
      f32x4 v0 = *(const f32x4*)s;
      f32x4 v1 = *(const f32x4*)(s + 4);
      unsigned* tp = (unsigned*)(T + hr * 138 + c8 * 8);
      tp[0] = pk2(v0.x, v0.y); tp[1] = pk2(v0.z, v0.w);
      tp[2] = pk2(v1.x, v1.y); tp[3] = pk2(v1.z, v1.w);
    }
    __syncthreads();
#pragma unroll
    for (int j = 0; j < 4; ++j) {
      int o = tid + j * 256;
      int fl = o >> 3, k8 = o & 7;
      unsigned qq[4];
#pragma unroll
      for (int p = 0; p < 4; ++p) {
        unsigned a0 = (unsigned short)T[(k8 * 8 + p * 2) * 138 + fl];
        unsigned a1 = (unsigned short)T[(k8 * 8 + p * 2 + 1) * 138 + fl];
        qq[p] = a0 | (a1 << 16);
      }
      uint4 q; q.x = qq[0]; q.y = qq[1]; q.z = qq[2]; q.w = qq[3];
      int set = kc * 2 + (k8 >> 2);
      int lane = (k8 & 3) * 16 + (fl & 15);
      int wvf = fl >> 6, fr = (fl >> 4) & 3;
      *(uint4*)(w1f + (size_t)(e * 4 + fq) * 32768 + set * 4096 + wvf * 2048 + fr * 512 +
                lane * 8) = q;
    }
  } else if (b < 768) {
    // w2 chunk: b2 = e*8 + fq*2 + kcc; 64 f-rows x 256 hd
    int b2 = b - 512;
    int e = b2 >> 3, fq = (b2 >> 1) & 3, kcc = b2 & 1;
    const float* src = w2 + (e * 512 + fq * 128 + kcc * 64) * 256;
    for (int c = tid; c < 2048; c += 256) {
      int fr = c >> 5, c8 = c & 31;
      const float* s = src + fr * 256 + c8 * 8;
      f32x4 v0 = *(const f32x4*)s;
      f32x4 v1 = *(const f32x4*)(s + 4);
      unsigned* tp = (unsigned*)(T + fr * 266 + c8 * 8);
      tp[0] = pk2(v0.x, v0.y); tp[1] = pk2(v0.z, v0.w);
      tp[2] = pk2(v1.x, v1.y); tp[3] = pk2(v1.z, v1.w);
    }
    __syncthreads();
#pragma unroll
    for (int j = 0; j < 8; ++j) {
      int o = tid + j * 256;
      int hd = o >> 3, k8 = o & 7;
      unsigned qq[4];
#pragma unroll
      for (int p = 0; p < 4; ++p) {
        unsigned a0 = (unsigned short)T[(k8 * 8 + p * 2) * 266 + hd];
        unsigned a1 = (unsigned short)T[(k8 * 8 + p * 2 + 1) * 266 + hd];
        qq[p] = a0 | (a1 << 16);
      }
      uint4 q; q.x = qq[0]; q.y = qq[1]; q.z = qq[2]; q.w = qq[3];
      int kc2 = kcc * 2 + (k8 >> 2);
      int lane = (k8 & 3) * 16 + (hd & 15);
      *(uint4*)(w2f + (size_t)(e * 4 + fq) * 32768 + kc2 * 8192 + (hd >> 4) * 512 +
                lane * 8) = q;
    }
  } else if (b < 776) {
    int b3 = b - 768;
    int fq = b3 >> 2, kc = b3 & 3;
    const float* src = Wp + (kc * 64) * 256 + fq * 128;
    for (int c = tid; c < 1024; c += 256) {
      int hr = c >> 4, c8 = c & 15;
      const float* s = src + hr * 256 + c8 * 8;
      f32x4 v0 = *(const f32x4*)s;
      f32x4 v1 = *(const f32x4*)(s + 4);
      unsigned* tp = (unsigned*)(T + hr * 138 + c8 * 8);
      tp[0] = pk2(v0.x, v0.y); tp[1] = pk2(v0.z, v0.w);
      tp[2] = pk2(v1.x, v1.y); tp[3] = pk2(v1.z, v1.w);
    }
    __syncthreads();
#pragma unroll
    for (int j = 0; j < 4; ++j) {
      int o = tid + j * 256;
      int fl = o >> 3, k8 = o & 7;
      unsigned qq[4];
#pragma unroll
      for (int p = 0; p < 4; ++p) {
        unsigned a0 = (unsigned short)T[(k8 * 8 + p * 2) * 138 + fl];
        unsigned a1 = (unsigned short)T[(k8 * 8 + p * 2 + 1) * 138 + fl];
        qq[p] = a0 | (a1 << 16);
      }
      uint4 q; q.x = qq[0]; q.y = qq[1]; q.z = qq[2]; q.w = qq[3];
      int off = (fl * 64 + k8 * 8) ^ ((fl & 7) << 3);
      *(uint4*)(wpt + b3 * 8192 + off) = q;
    }
  } else if (b < 792) {
    // wk: Wk[k][e] = sum_j Wq[k][j]*keys[e][j]; 8 blocks of 32 k-rows per Wq
    int b4 = b - 776;
    const float* Wq = (b4 >= 8) ? Wq2 : Wq1;
    float* Wk = (b4 >= 8) ? wk2 : wk1;
    const int kb = (b4 & 7) * 32;
    float* KT = (float*)T;  // [j 256][e 32], rotated: col = (e + j) & 31
    for (int i = tid; i < 8192; i += 256) {
      int e = i >> 8, j = i & 255;
      KT[j * 32 + ((e + j) & 31)] = keys[e * 256 + j];
    }
    __syncthreads();
    const int e = tid & 31, kk = (tid >> 5) * 2;  // 2 k-rows per thread
    f32x4 acc0 = (f32x4)(0.0f), acc1 = (f32x4)(0.0f);
    const float* wq0 = Wq + (size_t)(kb + kk) * 256;
#pragma unroll 4
    for (int j = 0; j < 256; j += 4) {
      f32x4 kt;
      kt.x = KT[j * 32 + ((e + j) & 31)];
      kt.y = KT[(j + 1) * 32 + ((e + j + 1) & 31)];
      kt.z = KT[(j + 2) * 32 + ((e + j + 2) & 31)];
      kt.w = KT[(j + 3) * 32 + ((e + j + 3) & 31)];
      acc0 += *(const f32x4*)(wq0 + j) * kt;
      acc1 += *(const f32x4*)(wq0 + 256 + j) * kt;
    }
    Wk[(kb + kk) * 32 + e] = acc0.x + acc0.y + acc0.z + acc0.w;
    Wk[(kb + kk + 1) * 32 + e] = acc1.x + acc1.y + acc1.z + acc1.w;
  } else {
    for (int i = tid; i < 2048; i += 256) dout[i] = 0.0f;
    if (tid == 0) dout[2048 + 4194304] = 0.0f;
  }
}

// ---------------- K2: input projection (MFMA) ----------------
#define P_LDS_W 67584
#define P_LDS_BP 100352
#define P_LDS_TOT 101376

__launch_bounds__(512, 2)
__global__ void k_proj(const float* __restrict__ xin, const unsigned short* __restrict__ wpt,
                       const float* __restrict__ bp, float* __restrict__ tokf,
                       unsigned short* __restrict__ tokb) {
  extern __shared__ char smem[];
  const int tid = threadIdx.x;
  const int tb = blockIdx.x * 128;
  const int w = tid >> 6, l = tid & 63, l15 = l & 15, l4 = l >> 4;

  for (int s = tid; s < 4096; s += 512) {
    int row = s >> 5, c8 = s & 31;
    const float* src = xin + (tb + row) * 256 + c8 * 8;
    f32x4 v0 = *(const f32x4*)src;
    f32x4 v1 = *(const f32x4*)(src + 4);
    uint4 pv;
    pv.x = pk2(v0.x, v0.y); pv.y = pk2(v0.z, v0.w);
    pv.z = pk2(v1.x, v1.y); pv.w = pk2(v1.z, v1.w);
    *(uint4*)(smem + row * 528 + c8 * 16) = pv;
  }
  if (tid < 256) ((float*)(smem + P_LDS_BP))[tid] = bp[tid];
  __syncthreads();

  const int wv_f = w >> 2, wv_t = w & 3;
  for (int fq = 0; fq < 2; ++fq) {
    f32x4 acc[8];
#pragma unroll
    for (int i = 0; i < 8; ++i) acc[i] = (f32x4)(0.0f);
    const char* cbase = (const char*)(wpt + (fq * 4) * 8192);
    {
      char* dst = smem + P_LDS_W;
      async16(dst + w * 2048, cbase + w * 2048 + l * 16);
      async16(dst + w * 2048 + 1024, cbase + w * 2048 + 1024 + l * 16);
    }
    __syncthreads();
    for (int kc = 0; kc < 4; ++kc) {
      int cur = kc & 1;
      if (kc < 3) {
        char* dst = smem + P_LDS_W + (cur ^ 1) * 16384;
        const char* src = cbase + (kc + 1) * 16384;
        async16(dst + w * 2048, src + w * 2048 + l * 16);
        async16(dst + w * 2048 + 1024, src + w * 2048 + 1024 + l * 16);
      }
      const char* Wc = smem + P_LDS_W + cur * 16384;
#pragma unroll
      for (int ks = 0; ks < 2; ++ks) {
        short8 af[4], bfr[2];
#pragma unroll
        for (int fr = 0; fr < 4; ++fr) {
          int frow = wv_f * 64 + fr * 16 + l15;
          int off = (frow * 128 + ks * 64 + l4 * 16) ^ ((frow & 7) << 4);
          af[fr] = *(const short8*)(Wc + off);
        }
#pragma unroll
        for (int tf = 0; tf < 2; ++tf) {
          int tok = wv_t * 32 + tf * 16 + l15;
          bfr[tf] = *(const short8*)(smem + tok * 528 + kc * 128 + ks * 64 + l4 * 16);
        }
#pragma unroll
        for (int fr = 0; fr < 4; ++fr)
#pragma unroll
          for (int tf = 0; tf < 2; ++tf)
            acc[fr * 2 + tf] = MFMA16(af[fr], bfr[tf], acc[fr * 2 + tf]);
      }
      __syncthreads();
    }
    const float* BP = (const float*)(smem + P_LDS_BP);
#pragma unroll
    for (int fr = 0; fr < 4; ++fr) {
      int hd0 = fq * 128 + wv_f * 64 + fr * 16 + l4 * 4;
      f32x4 bv = *(const f32x4*)(BP + hd0);
#pragma unroll
      for (int tf = 0; tf < 2; ++tf) {
        int tok = tb + wv_t * 32 + tf * 16 + l15;
        f32x4 o = acc[fr * 2 + tf] + bv;
        *(f32x4*)(tokf + tok * 256 + hd0) = o;
        uint2 hv; hv.x = pk2(o.x, o.y); hv.y = pk2(o.z, o.w);
        *(uint2*)(tokb + tok * 256 + hd0) = hv;
      }
    }
  }
}

// ---------------- K3: router 1 (fp32) ----------------
__global__ void k_router1(const float* __restrict__ tokf, const float* __restrict__ wk1,
                          float* __restrict__ probs1, int* __restrict__ top1) {
  __shared__ float WK[8192];
  const int tid = threadIdx.x;
  for (int i = tid; i < 8192; i += 256) WK[i] = wk1[i];
  __syncthreads();
  const int w = tid >> 6, l = tid & 63;
  const int e = l & 31, half = l >> 5;
  for (int tt = 0; tt < 16; ++tt) {
    int t = blockIdx.x * 64 + w * 16 + tt;
    const float* row = tokf + t * 256 + half * 128;
    const float* wkh = WK + half * 128 * 32 + e;
    float s = 0.f;
    for (int kk = 0; kk < 128; ++kk) s += row[kk] * wkh[kk * 32];
    s += __shfl_xor(s, 32);
    s *= 0.0625f;
    float m = s;
#pragma unroll
    for (int off = 16; off > 0; off >>= 1) m = fmaxf(m, __shfl_xor(m, off, 32));
    float ex = __expf(s - m);
    float sum = ex;
#pragma unroll
    for (int off = 16; off > 0; off >>= 1) sum += __shfl_xor(sum, off, 32);
    if (l < 32) probs1[t * 32 + e] = ex / sum;
    float bs = s; int bi = e;
#pragma unroll
    for (int off = 16; off > 0; off >>= 1) {
      float os = __shfl_xor(bs, off, 32);
      int oi = __shfl_xor(bi, off, 32);
      if (os > bs || (os == bs && oi < bi)) { bs = os; bi = oi; }
    }
    if (l == 0) top1[t] = bi;
  }
}

// ---------------- K4: fused expert bank (flatmm + 2-deep 3-ring, R8 struct) ----
#define B_PR 65536
#define B_B1 73728
#define B_TOT 106496

__launch_bounds__(512, 2)
__global__ void k_bank(const unsigned short* __restrict__ xg, const float* __restrict__ probsg,
                       const float* __restrict__ b1g, const unsigned short* __restrict__ w1f,
                       const unsigned short* __restrict__ w2f, float* __restrict__ partg) {
  extern __shared__ char smem[];
  const int tid = threadIdx.x;
  // XCD-coherent mapping: each XCD's blocks share one expert-group weight slab.
  const int xcd = blockIdx.x & 7;
  const int grp = xcd >> 2;
  const int tile = (xcd & 3) * 32 + (blockIdx.x >> 3);
  const int tb = tile * 128;
  const int w = tid >> 6, l = tid & 63, l15 = l & 15, l4 = l >> 4;
  const int wv_f = w >> 2, wv_t = w & 3;   // G1: 2 f-halves x 4 tok-groups
  const int wv_h = w >> 1, wv_t2 = w & 1;  // G2: 4 hd-groups x 2 tok-halves
  float* PRL = (float*)(smem + B_PR);
  float* B1L = (float*)(smem + B_B1);

  // stage probs (16e x 128tok) + b1 slab (16e x 512)
  for (int s = tid; s < 2048; s += 512)
    PRL[s] = probsg[(size_t)(tb + (s & 127)) * 32 + grp * 16 + (s >> 7)];
  for (int s = tid; s < 8192; s += 512) B1L[s] = b1g[grp * 8192 + s];

  // X fragments -> registers
  short8 xr[16];
#pragma unroll
  for (int tf = 0; tf < 2; ++tf)
#pragma unroll
    for (int kc = 0; kc < 4; ++kc)
#pragma unroll
      for (int ks = 0; ks < 2; ++ks) {
        int tok = tb + wv_t * 32 + tf * 16 + l15;
        xr[tf * 8 + kc * 2 + ks] =
            *(const short8*)(xg + (size_t)tok * 256 + kc * 64 + ks * 32 + l4 * 8);
      }
  __syncthreads();

  const unsigned short* w1e = w1f + (size_t)grp * 64 * 32768;
  const unsigned short* w2e = w2f + (size_t)grp * 64 * 32768;
  const int o1 = wv_f * 2048 + l * 8;
  const int o2 = wv_h * 2048 + l * 8;

  f32x4 acc2[16];
#pragma unroll
  for (int i = 0; i < 16; ++i) acc2[i] = (f32x4)(0.0f);

  short8 wb[3][4];
  LOAD4(wb[0], w1e + 0 * 4096 + o1);  // el0 set0
  LOAD4(wb[1], w1e + 1 * 4096 + o1);  // el0 set1
  int hcur = 0;

  for (int el = 0; el < 64; ++el) {
    const unsigned short* w1c = w1e + (size_t)el * 32768;
    const unsigned short* w2c = w2e + (size_t)el * 32768;
    const int e = el >> 2, fq = el & 3;

    // ---- G1: 8 sets, 2-deep prefetch (cross into G2 sets 0,1 at k=6,7)
    f32x4 acc1[8];
#pragma unroll
    for (int i = 0; i < 8; ++i) acc1[i] = (f32x4)(0.0f);
#pragma unroll
    for (int k = 0; k < 8; ++k) {
      if (k < 6) { LOAD4(wb[(k + 2) % 3], w1c + (k + 2) * 4096 + o1); }
      else       { LOAD4(wb[(k + 2) % 3], w2c + (k - 6) * 8192 + o2); }
      __builtin_amdgcn_s_setprio(1);
#pragma unroll
      for (int fr = 0; fr < 4; ++fr)
#pragma unroll
        for (int tf = 0; tf < 2; ++tf)
          acc1[fr * 2 + tf] = MFMA16(wb[k % 3][fr], xr[tf * 8 + k], acc1[fr * 2 + tf]);
      __builtin_amdgcn_s_setprio(0);
    }

    // ---- epilogue: h = relu(acc1 + b1)*p -> H[hcur]
    {
      const float* bb = B1L + e * 512 + fq * 128;
      const float* pp = PRL + e * 128;
      float p0 = pp[wv_t * 32 + l15];
      float p1 = pp[wv_t * 32 + 16 + l15];
      char* Hw = smem + hcur * 32768;
#pragma unroll
      for (int fr = 0; fr < 4; ++fr) {
        int f0 = wv_f * 64 + fr * 16 + l4 * 4;
        f32x4 bvv = *(const f32x4*)(bb + f0);
#pragma unroll
        for (int tf = 0; tf < 2; ++tf) {
          int tok = wv_t * 32 + tf * 16 + l15;
          float p = tf ? p1 : p0;
          f32x4 a = acc1[fr * 2 + tf];
          float h0 = fmaxf(a.x + bvv.x, 0.f) * p;
          float h1 = fmaxf(a.y + bvv.y, 0.f) * p;
          float h2 = fmaxf(a.z + bvv.z, 0.f) * p;
          float h3 = fmaxf(a.w + bvv.w, 0.f) * p;
          uint2 hv; hv.x = pk2(h0, h1); hv.y = pk2(h2, h3);
          *(uint2*)(Hw + ((tok * 256 + f0 * 2) ^ ((tok & 7) << 4))) = hv;
        }
      }
    }
    __syncthreads();  // single barrier per el (H dbuf)

    // ---- G2: 4 sets; prefetch G2 sets 2,3 then next-el G1 sets 0,1
    {
      const char* Hr = smem + hcur * 32768;
#pragma unroll
      for (int k = 8; k < 12; ++k) {
        const int t = k + 2;
        if (t < 12) { LOAD4(wb[t % 3], w2c + (t - 8) * 8192 + o2); }
        else if (el < 63) { LOAD4(wb[t % 3], w1c + 32768 + (t - 12) * 4096 + o1); }
        short8 b2f[4];
#pragma unroll
        for (int tf = 0; tf < 4; ++tf) {
          int tok = wv_t2 * 64 + tf * 16 + l15;
          b2f[tf] = *(const short8*)(
              Hr + ((tok * 256 + (k - 8) * 64 + l4 * 16) ^ ((tok & 7) << 4)));
        }
        __builtin_amdgcn_s_setprio(1);
#pragma unroll
        for (int hr = 0; hr < 4; ++hr)
#pragma unroll
          for (int tf = 0; tf < 4; ++tf)
            acc2[hr * 4 + tf] = MFMA16(wb[k % 3][hr], b2f[tf], acc2[hr * 4 + tf]);
        __builtin_amdgcn_s_setprio(0);
      }
    }
    hcur ^= 1;
  }

  float* pout = partg + (size_t)grp * 4194304;
#pragma unroll
  for (int hr = 0; hr < 4; ++hr) {
    int hd0 = wv_h * 64 + hr * 16 + l4 * 4;
#pragma unroll
    for (int tf = 0; tf < 4; ++tf) {
      int tok = tb + wv_t2 * 64 + tf * 16 + l15;
      *(f32x4*)(pout + (size_t)tok * 256 + hd0) = acc2[hr * 4 + tf];
    }
  }
}

// ---------------- K5: hop1 reduce + halt + router2 ----------------
#define M_PRB 65536
#define M_AUX 73728
#define M_TBL 106496
#define M_PSUM 110592
#define M_TOT 110656

__launch_bounds__(512)
__global__ void k_mid(const float* __restrict__ partg, const float* __restrict__ probs1,
                      const float* __restrict__ b2g, const float* __restrict__ hlg,
                      const float* __restrict__ hlb, const float* __restrict__ hwg,
                      const float* __restrict__ hbg, const float* __restrict__ wk2,
                      const float* __restrict__ tbias, const int* __restrict__ top1,
                      unsigned short* __restrict__ hop1b, float* __restrict__ haltg,
                      float* __restrict__ probs2, float* __restrict__ dout) {
  extern __shared__ char smem[];
  const int tid = threadIdx.x;
  const int tb = blockIdx.x * 64;
  float* ROWS = (float*)smem;
  float* PRB = (float*)(smem + M_PRB);
  float* AUX = (float*)(smem + M_AUX);

  for (int i = tid; i < 2048; i += 512) PRB[i] = probs1[tb * 32 + i];
  for (int i = tid; i < 8192; i += 512) AUX[i] = b2g[i];
  __syncthreads();

  for (int i = tid; i < 4096; i += 512) {
    int t = i >> 6, h4 = i & 63;
    size_t gi = (size_t)(tb + t) * 256 + h4 * 4;
    f32x4 v = *(const f32x4*)(partg + gi) + *(const f32x4*)(partg + 4194304 + gi);
    const float* pr = PRB + t * 32;
    for (int e = 0; e < 32; ++e) v += pr[e] * *(const f32x4*)(AUX + e * 256 + h4 * 4);
    *(f32x4*)(ROWS + t * 256 + h4 * 4) = v;
    uint2 hv; hv.x = pk2(v.x, v.y); hv.y = pk2(v.z, v.w);
    *(uint2*)(hop1b + gi) = hv;
  }
  __syncthreads();
  for (int i = tid; i < 8192; i += 512) AUX[i] = wk2[i];
  float* TBL = (float*)(smem + M_TBL);
  for (int i = tid; i < 1024; i += 512) TBL[i] = tbias[i];
  __syncthreads();

  const int w = tid >> 6, l = tid & 63;
  const int e = l & 31, half = l >> 5;
  float pond = 0.f;
  for (int tt = 0; tt < 8; ++tt) {
    int t = w * 8 + tt, tg = tb + t;
    const float* row = ROWS + t * 256;
    f32x4 x4 = *(const f32x4*)(row + l * 4);
    float mu = wsum64(x4.x + x4.y + x4.z + x4.w) * (1.f / 256.f);
    f32x4 d = x4 - mu;
    float var = wsum64(d.x * d.x + d.y * d.y + d.z * d.z + d.w * d.w) * (1.f / 256.f);
    float rstd = rsqrtf(var + 1e-5f);
    f32x4 g4 = *(const f32x4*)(hlg + l * 4);
    f32x4 b4 = *(const f32x4*)(hlb + l * 4);
    f32x4 w4 = *(const f32x4*)(hwg + l * 4);
    f32x4 y = d * rstd * g4 + b4;
    float z = wsum64(y.x * w4.x + y.y * w4.y + y.z * w4.z + y.w * w4.w);
    float hp = 1.f / (1.f + __expf(-(z + hbg[0])));
    if (l == 0) { haltg[tg] = hp; pond += 1.f - hp; }
    const float* rh = row + half * 128;
    const float* wkh = AUX + half * 128 * 32 + e;
    float sc = 0.f;
    for (int kk = 0; kk < 128; ++kk) sc += rh[kk] * wkh[kk * 32];
    sc += __shfl_xor(sc, 32);
    sc = sc * 0.0625f + TBL[top1[tg] * 32 + e];
    float m = sc;
#pragma unroll
    for (int off = 16; off > 0; off >>= 1) m = fmaxf(m, __shfl_xor(m, off, 32));
    float ex = __expf(sc - m);
    float sum = ex;
#pragma unroll
    for (int off = 16; off > 0; off >>= 1) sum += __shfl_xor(sum, off, 32);
    if (l < 32) probs2[tg * 32 + e] = ex / sum;
  }
  float* PS = (float*)(smem + M_PSUM);
  if (l == 0) PS[w] = pond;
  __syncthreads();
  if (tid == 0) {
    float tot = 0.f;
    for (int i = 0; i < 8; ++i) tot += PS[i];
    atomicAdd(dout + 2048 + 4194304, tot * (0.01f / 16384.f));
  }
}

// ---------------- K7: final mix + LN + pooled ----------------
#define F_PRB 65536
#define F_B2 73728
#define F_PSUM 106496
#define F_TOT 114688

__launch_bounds__(512)
__global__ void k_final(const float* __restrict__ partg, const float* __restrict__ probs2,
                        const float* __restrict__ b2g, const float* __restrict__ tokf,
                        const unsigned short* __restrict__ hop1b, const float* __restrict__ haltg,
                        const float* __restrict__ ng, const float* __restrict__ nbv,
                        float* __restrict__ dout) {
  extern __shared__ char smem[];
  const int tid = threadIdx.x;
  const int tb = blockIdx.x * 64;
  const int batch = blockIdx.x >> 5;
  float* ROWS = (float*)smem;
  float* PRB = (float*)(smem + F_PRB);
  float* B2L = (float*)(smem + F_B2);

  for (int i = tid; i < 2048; i += 512) PRB[i] = probs2[tb * 32 + i];
  for (int i = tid; i < 8192; i += 512) B2L[i] = b2g[i];
  __syncthreads();

  for (int i = tid; i < 4096; i += 512) {
    int t = i >> 6, h4 = i & 63;
    size_t gi = (size_t)(tb + t) * 256 + h4 * 4;
    f32x4 h2 = *(const f32x4*)(partg + gi) + *(const f32x4*)(partg + 4194304 + gi);
    const float* pr = PRB + t * 32;
    for (int e = 0; e < 32; ++e) h2 += pr[e] * *(const f32x4*)(B2L + e * 256 + h4 * 4);
    float hp = haltg[tb + t];
    uint2 h1v = *(const uint2*)(hop1b + gi);
    f32x4 h1;
    h1.x = bf2f(h1v.x & 0xffff); h1.y = bf2f(h1v.x >> 16);
    h1.z = bf2f(h1v.y & 0xffff); h1.w = bf2f(h1v.y >> 16);
    f32x4 tk = *(const f32x4*)(tokf + gi);
    f32x4 pre = tk + hp * h1 + (1.f - hp) * h2;
    *(f32x4*)(ROWS + t * 256 + h4 * 4) = pre;
  }
  __syncthreads();
  const int w = tid >> 6, l = tid & 63;
  f32x4 pacc = (f32x4)(0.0f);
  f32x4 g4 = *(const f32x4*)(ng + l * 4);
  f32x4 b4 = *(const f32x4*)(nbv + l * 4);
  for (int tt = 0; tt < 8; ++tt) {
    int t = w * 8 + tt, tg = tb + t;
    f32x4 x4 = *(const f32x4*)(ROWS + t * 256 + l * 4);
    float mu = wsum64(x4.x + x4.y + x4.z + x4.w) * (1.f / 256.f);
    f32x4 d = x4 - mu;
    float var = wsum64(d.x * d.x + d.y * d.y + d.z * d.z + d.w * d.w) * (1.f / 256.f);
    float rstd = rsqrtf(var + 1e-5f);
    f32x4 y = d * rstd * g4 + b4;
    *(f32x4*)(dout + 2048 + (size_t)tg * 256 + l * 4) = y;
    pacc += y;
  }
  float* PS = (float*)(smem + F_PSUM);
  *(f32x4*)(PS + w * 256 + l * 4) = pacc;
  __syncthreads();
  if (tid < 256) {
    float s = 0.f;
    for (int ww = 0; ww < 8; ++ww) s += PS[ww * 256 + tid];
    atomicAdd(dout + batch * 256 + tid, s * (1.f / 2048.f));
  }
}

extern "C" void kernel_launch(void* const* d_in, const int* in_sizes, int n_in,
                              void* d_out, int out_size, void* d_ws, size_t ws_size,
                              hipStream_t stream) {
  (void)in_sizes; (void)n_in; (void)out_size; (void)ws_size;
  const float* tokens_in = (const float*)d_in[0];
  const float* Wp = (const float*)d_in[1];
  const float* bp = (const float*)d_in[2];
  const float* Wq1 = (const float*)d_in[3];
  const float* Wq2 = (const float*)d_in[4];
  const float* keys = (const float*)d_in[5];
  const float* tbias = (const float*)d_in[6];
  const float* hlg = (const float*)d_in[7];
  const float* hlb = (const float*)d_in[8];
  const float* hw = (const float*)d_in[9];
  const float* hb = (const float*)d_in[10];
  const float* w1 = (const float*)d_in[11];
  const float* b1 = (const float*)d_in[12];
  const float* w2 = (const float*)d_in[13];
  const float* b2 = (const float*)d_in[14];
  const float* ng = (const float*)d_in[15];
  const float* nb = (const float*)d_in[16];
  float* out = (float*)d_out;
  char* ws = (char*)d_ws;

  unsigned short* w1f = (unsigned short*)(ws + 0);
  unsigned short* w2f = (unsigned short*)(ws + 8388608);
  unsigned short* wpt = (unsigned short*)(ws + 16777216);
  float* tokf = (float*)(ws + 16908288);
  unsigned short* tokb = (unsigned short*)(ws + 33685504);
  float* probs1 = (float*)(ws + 42074112);
  int* top1 = (int*)(ws + 44171264);
  unsigned short* hop1b = (unsigned short*)(ws + 44236800);
  float* haltg = (float*)(ws + 52625408);
  float* probs2 = (float*)(ws + 52690944);
  float* wk1 = (float*)(ws + 54788096);
  float* wk2 = (float*)(ws + 54820864);
  float* part = (float*)(ws + 54853632);  // 2 x 16384 x 256 f32

  k_prep<<<dim3(793), dim3(256), 0, stream>>>(w1, w2, Wp, Wq1, Wq2, keys,
                                              w1f, w2f, wpt, wk1, wk2, out);
  k_proj<<<dim3(128), dim3(512), P_LDS_TOT, stream>>>(tokens_in, wpt, bp, tokf, tokb);
  k_router1<<<dim3(256), dim3(256), 0, stream>>>(tokf, wk1, probs1, top1);
  k_bank<<<dim3(256), dim3(512), B_TOT, stream>>>(tokb, probs1, b1, w1f, w2f, part);
  k_mid<<<dim3(256), dim3(512), M_TOT, stream>>>(part, probs1, b2, hlg, hlb, hw, hb, wk2,
                                                 tbias, top1, hop1b, haltg, probs2, out);
  k_bank<<<dim3(256), dim3(512), B_TOT, stream>>>(hop1b, probs2, b1, w1f, w2f, part);
  k_final<<<dim3(256), dim3(512), F_TOT, stream>>>(part, probs2, b2, tokf, hop1b, haltg, ng, nb, out);
}